// Round 1
// baseline (1921.874 us; speedup 1.0000x reference)
//
#include <hip/hip_runtime.h>
#include <cmath>

#define DEVFN __device__ __forceinline__

// ---- problem constants ----
constexpr int B_ = 8;
constexpr int C_ = 256;
constexpr int H_ = 160;
constexpr int W_ = 160;
constexpr int HD_ = 40;
constexpr int WD_ = 40;
constexpr int N_ = 1600;                    // HD_*WD_
constexpr int PLANE_ = C_ * N_;             // 409600 floats per batch per tensor
constexpr size_t TSZ_ = (size_t)B_ * PLANE_; // 3,276,800 floats (13.1 MB)
constexpr float ASCALE_ = 0.0625f;          // 1/sqrt(256)

// ---- static device scratch (avoids any ws_size assumption; every byte is
// written before read on every call, so harness re-poisoning is irrelevant) ----
__device__ __attribute__((aligned(16))) float g_xr[TSZ_]; // z_rgb downsampled [b][c][n]
__device__ __attribute__((aligned(16))) float g_xi[TSZ_]; // z_ir  downsampled
__device__ __attribute__((aligned(16))) float g_qr[TSZ_];
__device__ __attribute__((aligned(16))) float g_ki[TSZ_];
__device__ __attribute__((aligned(16))) float g_vi[TSZ_];
__device__ __attribute__((aligned(16))) float g_qi[TSZ_];
__device__ __attribute__((aligned(16))) float g_kr[TSZ_];
__device__ __attribute__((aligned(16))) float g_vr[TSZ_];
__device__ __attribute__((aligned(16))) float g_zr[TSZ_]; // z'_rgb
__device__ __attribute__((aligned(16))) float g_zi[TSZ_]; // z'_ir
__device__ __attribute__((aligned(16))) float g_h1[TSZ_]; // h_rgb
__device__ __attribute__((aligned(16))) float g_h2[TSZ_]; // h_ir
__device__ __attribute__((aligned(16))) float g_fd[TSZ_]; // fused (downsampled)

DEVFN float sigm(float x) { return 1.f / (1.f + __expf(-x)); }

// ---------------------------------------------------------------------------
// K1: downsample 160->40. frac==0.5 exactly => 2x2 average at offset (1,1).
// out tokens [b][c][n], n = i*40+j. grid.y selects rgb/ir.
// ---------------------------------------------------------------------------
__global__ __launch_bounds__(256) void k_down(const float* __restrict__ zr,
                                              const float* __restrict__ zi) {
    int idx = blockIdx.x * 256 + threadIdx.x;       // over TSZ_
    const float* in = blockIdx.y ? zi : zr;
    float* out = blockIdx.y ? g_xi : g_xr;
    if (idx >= (int)TSZ_) return;
    int n = idx % N_;
    int bc = idx / N_;
    int i = n / WD_, j = n % WD_;
    const float* p = in + (size_t)bc * (H_ * W_) + (4 * i + 1) * W_ + (4 * j + 1);
    out[idx] = 0.25f * (p[0] + p[1] + p[W_] + p[W_ + 1]);
}

// ---------------------------------------------------------------------------
// K2/K4a: conv1x1 GEMM: y[o][n] = act( sum_c W[o][c]*x[c][n] + bias[o] )
// 64x64 tile, BK=16, 256 threads, 4x4 per thread.
// STAGE 0: 6 QKV sets (no act). STAGE 1: 2 proj sets (tanh).
// ---------------------------------------------------------------------------
struct ConvArgs {
    const float* W[6];
    const float* b[6];
};

template <int STAGE>
__global__ __launch_bounds__(256) void k_conv(ConvArgs a) {
    constexpr int NSETS = (STAGE == 0) ? 6 : 2;
    __shared__ __attribute__((aligned(16))) float As[16][64]; // [k][o]
    __shared__ __attribute__((aligned(16))) float Bs[16][64]; // [k][n]
    int tid = threadIdx.x;
    int set = blockIdx.z % NSETS;
    int bb = blockIdx.z / NSETS;
    const float* x;
    float* y;
    if (STAGE == 0) {
        switch (set) {
            case 0: x = g_xr; y = g_qr; break;
            case 1: x = g_xi; y = g_ki; break;
            case 2: x = g_xi; y = g_vi; break;
            case 3: x = g_xi; y = g_qi; break;
            case 4: x = g_xr; y = g_kr; break;
            default: x = g_xr; y = g_vr; break;
        }
    } else {
        if (set == 0) { x = g_zr; y = g_h1; }
        else          { x = g_zi; y = g_h2; }
    }
    const float* Wm = a.W[set];
    const float* bias = a.b[set];
    x += (size_t)bb * PLANE_;
    y += (size_t)bb * PLANE_;
    int n0 = blockIdx.x * 64;
    int o0 = blockIdx.y * 64;

    int ar = tid >> 2;            // A row (o), 0..63
    int ac4 = (tid & 3) * 4;      // A col (k)
    int br = tid >> 4;            // B row (k), 0..15
    int bc4 = (tid & 15) * 4;     // B col (n)
    int to4 = (tid >> 4) * 4;     // thread o base
    int tn4 = (tid & 15) * 4;     // thread n base

    float acc[4][4] = {};
    for (int k0 = 0; k0 < 256; k0 += 16) {
        float4 av = *(const float4*)&Wm[(o0 + ar) * 256 + k0 + ac4];
        float4 bv = *(const float4*)&x[(size_t)(k0 + br) * N_ + n0 + bc4];
        __syncthreads();
        As[ac4 + 0][ar] = av.x; As[ac4 + 1][ar] = av.y;
        As[ac4 + 2][ar] = av.z; As[ac4 + 3][ar] = av.w;
        *(float4*)&Bs[br][bc4] = bv;
        __syncthreads();
#pragma unroll
        for (int kk = 0; kk < 16; ++kk) {
            float4 a4 = *(const float4*)&As[kk][to4];
            float4 b4 = *(const float4*)&Bs[kk][tn4];
            acc[0][0] += a4.x * b4.x; acc[0][1] += a4.x * b4.y; acc[0][2] += a4.x * b4.z; acc[0][3] += a4.x * b4.w;
            acc[1][0] += a4.y * b4.x; acc[1][1] += a4.y * b4.y; acc[1][2] += a4.y * b4.z; acc[1][3] += a4.y * b4.w;
            acc[2][0] += a4.z * b4.x; acc[2][1] += a4.z * b4.y; acc[2][2] += a4.z * b4.z; acc[2][3] += a4.z * b4.w;
            acc[3][0] += a4.w * b4.x; acc[3][1] += a4.w * b4.y; acc[3][2] += a4.w * b4.z; acc[3][3] += a4.w * b4.w;
        }
    }
#pragma unroll
    for (int i = 0; i < 4; ++i) {
        float bi = bias[o0 + to4 + i];
        float4 v;
        v.x = acc[i][0] + bi; v.y = acc[i][1] + bi; v.z = acc[i][2] + bi; v.w = acc[i][3] + bi;
        if (STAGE == 1) { v.x = tanhf(v.x); v.y = tanhf(v.y); v.z = tanhf(v.z); v.w = tanhf(v.w); }
        *(float4*)&y[(size_t)(o0 + to4 + i) * N_ + n0 + tn4] = v;
    }
}

// ---------------------------------------------------------------------------
// K3: flash cross-attention (fp32). Per block: (batch, dir, 64-q tile).
// Layouts are channel-major [C][N]. Online softmax, O accumulated in regs.
// ---------------------------------------------------------------------------
__global__ __launch_bounds__(256) void k_attn() {
    __shared__ __attribute__((aligned(16))) float sQ[64][68];  // [c'][q]
    __shared__ __attribute__((aligned(16))) float sK[64][68];  // [c'][k]
    __shared__ __attribute__((aligned(16))) float sS[64][68];  // [q][k] scores / P
    __shared__ __attribute__((aligned(16))) float sVt[64][68]; // [k][c'] (and O transpose at end)
    __shared__ float sM[64], sL[64], sAlpha[64];

    int tid = threadIdx.x;
    int q0 = blockIdx.x * 64;
    int dir = blockIdx.y;
    int bb = blockIdx.z;
    const float *Q, *K, *V;
    float* O;
    if (dir == 0) { Q = g_qr; K = g_ki; V = g_vi; O = g_zr; }
    else          { Q = g_qi; K = g_kr; V = g_vr; O = g_zi; }
    size_t boff = (size_t)bb * PLANE_;
    Q += boff; K += boff; V += boff; O += boff;

    int lr = tid >> 4;            // staging row group 0..15
    int lc4 = (tid & 15) * 4;     // staging col
    int qi4 = (tid & 15) * 4;     // S compute: q base
    int ki4 = (tid >> 4) * 4;     // S compute: k base
    int sq = tid >> 2, spart = tid & 3;  // softmax: 4 threads/row
    int pq4 = (tid >> 4) * 4;     // PV: 4 q rows
    int pc4 = (tid & 15) * 4;     // PV: 4 channels within 64-chunk

    float Oacc[4][16];            // [q'][chunk*4 + c']
#pragma unroll
    for (int i = 0; i < 4; ++i)
#pragma unroll
        for (int c = 0; c < 16; ++c) Oacc[i][c] = 0.f;

    if (tid < 64) { sM[tid] = -1e30f; sL[tid] = 0.f; }

    for (int k0 = 0; k0 < N_; k0 += 64) {
        // ---- S = scale * Q^T K over 4 c-chunks ----
        float acc[4][4] = {};
        for (int cc = 0; cc < 256; cc += 64) {
            float4 qv[4], kv[4];
#pragma unroll
            for (int r = 0; r < 4; ++r) {
                qv[r] = *(const float4*)&Q[(size_t)(cc + lr + 16 * r) * N_ + q0 + lc4];
                kv[r] = *(const float4*)&K[(size_t)(cc + lr + 16 * r) * N_ + k0 + lc4];
            }
            __syncthreads();
#pragma unroll
            for (int r = 0; r < 4; ++r) {
                *(float4*)&sQ[lr + 16 * r][lc4] = qv[r];
                *(float4*)&sK[lr + 16 * r][lc4] = kv[r];
            }
            __syncthreads();
#pragma unroll 16
            for (int cp = 0; cp < 64; ++cp) {
                float4 aq = *(const float4*)&sQ[cp][qi4];
                float4 bk = *(const float4*)&sK[cp][ki4];
                acc[0][0] += aq.x * bk.x; acc[0][1] += aq.x * bk.y; acc[0][2] += aq.x * bk.z; acc[0][3] += aq.x * bk.w;
                acc[1][0] += aq.y * bk.x; acc[1][1] += aq.y * bk.y; acc[1][2] += aq.y * bk.z; acc[1][3] += aq.y * bk.w;
                acc[2][0] += aq.z * bk.x; acc[2][1] += aq.z * bk.y; acc[2][2] += aq.z * bk.z; acc[2][3] += aq.z * bk.w;
                acc[3][0] += aq.w * bk.x; acc[3][1] += aq.w * bk.y; acc[3][2] += aq.w * bk.z; acc[3][3] += aq.w * bk.w;
            }
            __syncthreads();
        }
        // write scaled scores to LDS
#pragma unroll
        for (int i = 0; i < 4; ++i) {
            float4 v;
            v.x = acc[i][0] * ASCALE_; v.y = acc[i][1] * ASCALE_;
            v.z = acc[i][2] * ASCALE_; v.w = acc[i][3] * ASCALE_;
            *(float4*)&sS[qi4 + i][ki4] = v;
        }
        __syncthreads();
        // ---- online softmax (4 threads per row, bank-staggered scans) ----
        {
            float mo = sM[sq];
            float rm = -1e30f;
#pragma unroll
            for (int jj = 0; jj < 16; ++jj) {
                int j = (spart * 16 + jj + sq * 4) & 63;
                rm = fmaxf(rm, sS[sq][j]);
            }
            rm = fmaxf(rm, __shfl_xor(rm, 1));
            rm = fmaxf(rm, __shfl_xor(rm, 2));
            float mn = fmaxf(mo, rm);
            float rs = 0.f;
#pragma unroll
            for (int jj = 0; jj < 16; ++jj) {
                int j = (spart * 16 + jj + sq * 4) & 63;
                float p = __expf(sS[sq][j] - mn);
                sS[sq][j] = p;
                rs += p;
            }
            rs += __shfl_xor(rs, 1);
            rs += __shfl_xor(rs, 2);
            if (spart == 0) {
                sAlpha[sq] = __expf(mo - mn);
                sM[sq] = mn;
                sL[sq] = sL[sq] * sAlpha[sq] + rs;
            }
        }
        __syncthreads();
        // ---- rescale O ----
        float alv[4];
#pragma unroll
        for (int i = 0; i < 4; ++i) alv[i] = sAlpha[pq4 + i];
#pragma unroll
        for (int i = 0; i < 4; ++i)
#pragma unroll
            for (int c = 0; c < 16; ++c) Oacc[i][c] *= alv[i];
        // ---- O += P V over 4 c-chunks (V transposed into LDS) ----
        for (int ch = 0; ch < 4; ++ch) {
            float4 vv[4];
#pragma unroll
            for (int r = 0; r < 4; ++r)
                vv[r] = *(const float4*)&V[(size_t)(ch * 64 + lr + 16 * r) * N_ + k0 + lc4];
            __syncthreads();
#pragma unroll
            for (int r = 0; r < 4; ++r) {
                int c = lr + 16 * r;
                sVt[lc4 + 0][c] = vv[r].x; sVt[lc4 + 1][c] = vv[r].y;
                sVt[lc4 + 2][c] = vv[r].z; sVt[lc4 + 3][c] = vv[r].w;
            }
            __syncthreads();
#pragma unroll 4
            for (int k4 = 0; k4 < 64; k4 += 4) {
                float pr[4][4];
#pragma unroll
                for (int i = 0; i < 4; ++i) {
                    float4 t = *(const float4*)&sS[pq4 + i][k4];
                    pr[i][0] = t.x; pr[i][1] = t.y; pr[i][2] = t.z; pr[i][3] = t.w;
                }
#pragma unroll
                for (int kk = 0; kk < 4; ++kk) {
                    float4 v4 = *(const float4*)&sVt[k4 + kk][pc4];
#pragma unroll
                    for (int i = 0; i < 4; ++i) {
                        Oacc[i][ch * 4 + 0] += pr[i][kk] * v4.x;
                        Oacc[i][ch * 4 + 1] += pr[i][kk] * v4.y;
                        Oacc[i][ch * 4 + 2] += pr[i][kk] * v4.z;
                        Oacc[i][ch * 4 + 3] += pr[i][kk] * v4.w;
                    }
                }
            }
        }
    }
    // ---- finalize: divide by l, transpose through LDS, coalesced store ----
    float linv[4];
#pragma unroll
    for (int i = 0; i < 4; ++i) linv[i] = 1.f / sL[pq4 + i];
    for (int ch = 0; ch < 4; ++ch) {
        __syncthreads();
#pragma unroll
        for (int i = 0; i < 4; ++i)
#pragma unroll
            for (int j = 0; j < 4; ++j)
                sVt[pc4 + j][pq4 + i] = Oacc[i][ch * 4 + j] * linv[i];
        __syncthreads();
#pragma unroll
        for (int r = 0; r < 4; ++r) {
            int c = lr + 16 * r;
            float4 v = *(const float4*)&sVt[c][lc4];
            *(float4*)&O[(size_t)(ch * 64 + c) * N_ + q0 + lc4] = v;
        }
    }
}

// ---------------------------------------------------------------------------
// K4b: gate GEMM (K=512 over [z'_rgb ; z'_ir]) + full fuse epilogue:
// z = sigmoid(sigmoid(g + bz) + t_embed); fused = z*h_rgb + (1-z)*h_ir
// ---------------------------------------------------------------------------
__global__ __launch_bounds__(256) void k_gate(const float* __restrict__ Wg,
                                              const float* __restrict__ bg,
                                              const float* __restrict__ temb,
                                              const int* __restrict__ tidx) {
    __shared__ __attribute__((aligned(16))) float As[16][64];
    __shared__ __attribute__((aligned(16))) float Bs[16][64];
    int tid = threadIdx.x;
    int bb = blockIdx.z;
    int n0 = blockIdx.x * 64;
    int o0 = blockIdx.y * 64;
    const float* zrp = g_zr + (size_t)bb * PLANE_;
    const float* zip = g_zi + (size_t)bb * PLANE_;
    const float* h1p = g_h1 + (size_t)bb * PLANE_;
    const float* h2p = g_h2 + (size_t)bb * PLANE_;
    float* fdp = g_fd + (size_t)bb * PLANE_;

    int ar = tid >> 2;
    int ac4 = (tid & 3) * 4;
    int br = tid >> 4;
    int bc4 = (tid & 15) * 4;
    int to4 = (tid >> 4) * 4;
    int tn4 = (tid & 15) * 4;

    float acc[4][4] = {};
    for (int k0 = 0; k0 < 512; k0 += 16) {
        float4 av = *(const float4*)&Wg[(o0 + ar) * 512 + k0 + ac4];
        int krow = k0 + br;
        const float* brow = (krow < 256) ? (zrp + (size_t)krow * N_)
                                         : (zip + (size_t)(krow - 256) * N_);
        float4 bv = *(const float4*)&brow[n0 + bc4];
        __syncthreads();
        As[ac4 + 0][ar] = av.x; As[ac4 + 1][ar] = av.y;
        As[ac4 + 2][ar] = av.z; As[ac4 + 3][ar] = av.w;
        *(float4*)&Bs[br][bc4] = bv;
        __syncthreads();
#pragma unroll
        for (int kk = 0; kk < 16; ++kk) {
            float4 a4 = *(const float4*)&As[kk][to4];
            float4 b4 = *(const float4*)&Bs[kk][tn4];
            acc[0][0] += a4.x * b4.x; acc[0][1] += a4.x * b4.y; acc[0][2] += a4.x * b4.z; acc[0][3] += a4.x * b4.w;
            acc[1][0] += a4.y * b4.x; acc[1][1] += a4.y * b4.y; acc[1][2] += a4.y * b4.z; acc[1][3] += a4.y * b4.w;
            acc[2][0] += a4.z * b4.x; acc[2][1] += a4.z * b4.y; acc[2][2] += a4.z * b4.z; acc[2][3] += a4.z * b4.w;
            acc[3][0] += a4.w * b4.x; acc[3][1] += a4.w * b4.y; acc[3][2] += a4.w * b4.z; acc[3][3] += a4.w * b4.w;
        }
    }
    int t = tidx[bb];
#pragma unroll
    for (int i = 0; i < 4; ++i) {
        int o = o0 + to4 + i;
        float te = temb[t * 256 + o];
        float bgv = bg[o];
        float4 h1v = *(const float4*)&h1p[(size_t)o * N_ + n0 + tn4];
        float4 h2v = *(const float4*)&h2p[(size_t)o * N_ + n0 + tn4];
        float4 res;
        {
            float zz = sigm(sigm(acc[i][0] + bgv) + te);
            res.x = zz * h1v.x + (1.f - zz) * h2v.x;
        }
        {
            float zz = sigm(sigm(acc[i][1] + bgv) + te);
            res.y = zz * h1v.y + (1.f - zz) * h2v.y;
        }
        {
            float zz = sigm(sigm(acc[i][2] + bgv) + te);
            res.z = zz * h1v.z + (1.f - zz) * h2v.z;
        }
        {
            float zz = sigm(sigm(acc[i][3] + bgv) + te);
            res.w = zz * h1v.w + (1.f - zz) * h2v.w;
        }
        *(float4*)&fdp[(size_t)o * N_ + n0 + tn4] = res;
    }
}

// ---------------------------------------------------------------------------
// K5: upsample 40->160 bilinear (align_corners=False), one (b,c) plane/block.
// ---------------------------------------------------------------------------
__global__ __launch_bounds__(256) void k_up(float* __restrict__ out) {
    __shared__ float sp[1600];
    int bc = blockIdx.x;                       // 0..2047
    const float* p = g_fd + (size_t)bc * N_;
    float* o = out + (size_t)bc * (H_ * W_);
    int tid = threadIdx.x;
    for (int t = tid; t < 1600; t += 256) sp[t] = p[t];
    __syncthreads();
    for (int t = tid; t < H_ * W_; t += 256) {
        int i = t / W_, j = t % W_;
        float si = fmaxf(0.25f * i - 0.375f, 0.f);
        int i0 = (int)si;
        float fi = si - i0;
        int i1 = min(i0 + 1, 39);
        float sj = fmaxf(0.25f * j - 0.375f, 0.f);
        int j0 = (int)sj;
        float fj = sj - j0;
        int j1 = min(j0 + 1, 39);
        float v00 = sp[i0 * 40 + j0], v01 = sp[i0 * 40 + j1];
        float v10 = sp[i1 * 40 + j0], v11 = sp[i1 * 40 + j1];
        float r0 = v00 + (v01 - v00) * fj;
        float r1 = v10 + (v11 - v10) * fj;
        o[t] = r0 + (r1 - r0) * fi;
    }
}

// ---------------------------------------------------------------------------
extern "C" void kernel_launch(void* const* d_in, const int* in_sizes, int n_in,
                              void* d_out, int out_size, void* d_ws, size_t ws_size,
                              hipStream_t stream) {
    (void)in_sizes; (void)n_in; (void)out_size; (void)d_ws; (void)ws_size;
    const float* z_rgb = (const float*)d_in[0];
    const float* z_ir  = (const float*)d_in[1];
    const int*   tidx  = (const int*)d_in[2];
    const float* Wq_rgb = (const float*)d_in[3];  const float* bq_rgb = (const float*)d_in[4];
    const float* Wk_ir  = (const float*)d_in[5];  const float* bk_ir  = (const float*)d_in[6];
    const float* Wv_ir  = (const float*)d_in[7];  const float* bv_ir  = (const float*)d_in[8];
    const float* Wq_ir  = (const float*)d_in[9];  const float* bq_ir  = (const float*)d_in[10];
    const float* Wk_rgb = (const float*)d_in[11]; const float* bk_rgb = (const float*)d_in[12];
    const float* Wv_rgb = (const float*)d_in[13]; const float* bv_rgb = (const float*)d_in[14];
    const float* Wrgb_p = (const float*)d_in[15]; const float* brgb_p = (const float*)d_in[16];
    const float* Wir_p  = (const float*)d_in[17]; const float* bir_p  = (const float*)d_in[18];
    const float* Wz     = (const float*)d_in[19]; const float* bz     = (const float*)d_in[20];
    const float* temb   = (const float*)d_in[21];
    float* out = (float*)d_out;

    k_down<<<dim3((unsigned)(TSZ_ / 256), 2, 1), 256, 0, stream>>>(z_rgb, z_ir);

    ConvArgs qa = {};
    qa.W[0] = Wq_rgb; qa.b[0] = bq_rgb;
    qa.W[1] = Wk_ir;  qa.b[1] = bk_ir;
    qa.W[2] = Wv_ir;  qa.b[2] = bv_ir;
    qa.W[3] = Wq_ir;  qa.b[3] = bq_ir;
    qa.W[4] = Wk_rgb; qa.b[4] = bk_rgb;
    qa.W[5] = Wv_rgb; qa.b[5] = bv_rgb;
    k_conv<0><<<dim3(25, 4, B_ * 6), 256, 0, stream>>>(qa);

    k_attn<<<dim3(25, 2, B_), 256, 0, stream>>>();

    ConvArgs pa = {};
    pa.W[0] = Wrgb_p; pa.b[0] = brgb_p;
    pa.W[1] = Wir_p;  pa.b[1] = bir_p;
    k_conv<1><<<dim3(25, 4, B_ * 2), 256, 0, stream>>>(pa);

    k_gate<<<dim3(25, 4, B_), 256, 0, stream>>>(Wz, bz, temb, tidx);

    k_up<<<dim3(B_ * C_), 256, 0, stream>>>(out);
}